// Round 7
// baseline (123.877 us; speedup 1.0000x reference)
//
#include <hip/hip_runtime.h>

#define B 2
#define N 64
#define D 256
#define H 8
#define DK 32
#define M (B * N * N) // 8192

typedef __attribute__((ext_vector_type(8))) short bf16x8;
typedef __attribute__((ext_vector_type(4))) float f32x4;
typedef __attribute__((ext_vector_type(2))) float f32x2;

// P is head-major: 4 proj planes of [b][h][r1*64+r2][32] bf16
#define PROJ_ELEMS (2097152)  // B*H*4096*32

__device__ __forceinline__ ushort f2b(float f) {
    union { float f; unsigned u; } v; v.f = f;
    unsigned r = v.u + 0x7fffu + ((v.u >> 16) & 1u); // RNE
    return (ushort)(r >> 16);
}
__device__ __forceinline__ float b2f(ushort u) {
    union { unsigned u; float f; } v; v.u = ((unsigned)u) << 16; return v.f;
}
// unpack 2 packed bf16 (u32) -> float2
__device__ __forceinline__ f32x2 up2(unsigned u) {
    union { unsigned u; float f; } lo, hi;
    lo.u = u << 16; hi.u = u & 0xffff0000u;
    f32x2 r; r.x = lo.f; r.y = hi.f; return r;
}

// async 16B/lane global->LDS (dst = wave-uniform base + lane*16)
__device__ __forceinline__ void glds16(const ushort* g, ushort* l) {
    __builtin_amdgcn_global_load_lds(
        (const __attribute__((address_space(1))) unsigned int*)g,
        (__attribute__((address_space(3))) unsigned int*)l, 16, 0, 0);
}

// ---------------------------------------------------------------------------
// Cast: state f32 -> bf16; 5 weights -> Wcat[1280][256] bf16; biases -> f32.
// ---------------------------------------------------------------------------
__global__ __launch_bounds__(256) void cast_all(const float* __restrict__ state,
                                                const float* __restrict__ W_lk, const float* __restrict__ W_rk,
                                                const float* __restrict__ W_lv, const float* __restrict__ W_rv,
                                                const float* __restrict__ W_o,
                                                const float* __restrict__ b_lk, const float* __restrict__ b_rk,
                                                const float* __restrict__ b_lv, const float* __restrict__ b_rv,
                                                const float* __restrict__ b_o,
                                                ushort* __restrict__ state_bf,
                                                ushort* __restrict__ Wcat,
                                                float* __restrict__ bias_cat) {
    const int gid = blockIdx.x * 256 + threadIdx.x;
    const float* Ws[5] = {W_lk, W_rk, W_lv, W_rv, W_o};
    const float* bs[5] = {b_lk, b_rk, b_lv, b_rv, b_o};

    if (gid < 1280) bias_cat[gid] = bs[gid >> 8][gid & 255];

    if (gid < 524288) {
        float4 v = *(const float4*)&state[(size_t)gid * 4];
        ushort4 o = {f2b(v.x), f2b(v.y), f2b(v.z), f2b(v.w)};
        *(ushort4*)&state_bf[(size_t)gid * 4] = o;
    } else {
        int u = gid - 524288;            // 0..81919
        int row = u >> 6;                // 0..1279
        int k4 = (u & 63) * 4;
        const float* W = Ws[row >> 8];
        float4 v = *(const float4*)&W[(size_t)(row & 255) * 256 + k4];
        ushort4 o = {f2b(v.x), f2b(v.y), f2b(v.z), f2b(v.w)};
        *(ushort4*)&Wcat[(size_t)row * 256 + k4] = o;
    }
}

// ---------------------------------------------------------------------------
// bf16 MFMA GEMM, v10 (unchanged): BM x 128 tile, 4 waves, pipelined staging.
// ---------------------------------------------------------------------------
template <int BF16OUT, int RELAYOUT, int BM>
__global__ __launch_bounds__(256) void gemm_mfma(const ushort* __restrict__ A,
                                                 const ushort* __restrict__ Bw,
                                                 const float* __restrict__ bias,
                                                 void* __restrict__ Cv, int ldc) {
    constexpr int IR = BM / 32;  // 128 -> 4, 64 -> 2 (acc row-frags per wave)
    __shared__ __align__(16) ushort As[2][2][BM * 32];
    __shared__ __align__(16) ushort Bs[2][2][128 * 32];
    const int tid = threadIdx.x;
    const int lane = tid & 63;
    const int wave = tid >> 6;
    const int wm = (wave & 1) * (BM / 2);
    const int wn = (wave >> 1) * 64;
    const int row0 = blockIdx.x * BM;
    const int col0 = blockIdx.y * 128;

    const int lr = lane >> 2;        // 0..15
    const int lkq = (lane & 3) * 8;  // {0,8,16,24}

    const int arow = (BM == 128) ? (wave * 32) : (wave * 16);
    const ushort* gA0 = A + (size_t)(row0 + arow + lr) * 256 + lkq;
    const ushort* gA1 = gA0 + 16 * 256;  // BM==128 only
    const ushort* gB0 = Bw + (size_t)(col0 + wave * 32 + lr) * 256 + lkq;
    const ushort* gB1 = gB0 + 16 * 256;

    const int fr = lane & 15;
    const int fk = (lane >> 4) * 8;

    f32x4 acc[IR][4] = {};

    auto stage2 = [&](int grp) {
        const int buf = grp & 1;
#pragma unroll
        for (int p = 0; p < 2; ++p) {
            const int ko = (grp * 2 + p) * 32;
            glds16(gA0 + ko, &As[buf][p][arow * 32]);
            if (BM == 128) glds16(gA1 + ko, &As[buf][p][(arow + 16) * 32]);
            glds16(gB0 + ko, &Bs[buf][p][(wave * 32) * 32]);
            glds16(gB1 + ko, &Bs[buf][p][(wave * 32 + 16) * 32]);
        }
    };

    stage2(0);
    __syncthreads();  // drain prologue

    for (int it = 0; it < 4; ++it) {
        if (it < 3) stage2(it + 1);  // issue next pair; drains at loop barrier
        const int buf = it & 1;
#pragma unroll
        for (int p = 0; p < 2; ++p) {
            bf16x8 af[IR], bf[4];
#pragma unroll
            for (int i = 0; i < IR; ++i)
                af[i] = *(const bf16x8*)&As[buf][p][(wm + i * 16 + fr) * 32 + fk];
#pragma unroll
            for (int j = 0; j < 4; ++j)
                bf[j] = *(const bf16x8*)&Bs[buf][p][(wn + j * 16 + fr) * 32 + fk];
#pragma unroll
            for (int i = 0; i < IR; ++i)
#pragma unroll
                for (int j = 0; j < 4; ++j)
                    acc[i][j] = __builtin_amdgcn_mfma_f32_16x16x32_bf16(af[i], bf[j], acc[i][j], 0, 0, 0);
        }
        __syncthreads();  // drain stage(it+1); protect buf reuse
    }

#pragma unroll
    for (int j = 0; j < 4; ++j) {
        const int col = col0 + wn + j * 16 + (lane & 15);
        const float bv = bias[col];
#pragma unroll
        for (int i = 0; i < IR; ++i) {
            const int rbase = row0 + wm + i * 16 + (lane >> 4) * 4;
#pragma unroll
            for (int r = 0; r < 4; ++r) {
                float o = acc[i][j][r] + bv;
                if (RELAYOUT) {
                    const int row = rbase + r;
                    const int bb = row >> 12, rr = row & 4095;
                    const int proj = col >> 8, hh = (col >> 5) & 7, dk = col & 31;
                    ((ushort*)Cv)[(size_t)proj * PROJ_ELEMS +
                                  ((size_t)(bb * 8 + hh) * 4096 + rr) * 32 + dk] = f2b(o);
                } else if (BF16OUT) {
                    ((ushort*)Cv)[(size_t)(rbase + r) * ldc + col] = f2b(o);
                } else {
                    ((float*)Cv)[(size_t)(rbase + r) * ldc + col] = o;
                }
            }
        }
    }
}

// ---------------------------------------------------------------------------
// FUSED scores + online-softmax + gated combine, v12.
// r6 diagnosis: attn = 46.9us, latency-bound (VALU 24%, HBM 8%, occ 20%) —
// ALL global reads are cold HBM (~900cy) with pipelines of only 200-500cy.
// v12: everything flows through LDS with a FULL-CHUNK prefetch distance.
//  - a-chunk 16; LK/RK/LV/RV all staged via glds16, double-buffered:
//    4 planes x 2 bufs x 16KB = 128KB; + atts 20KB = 150.5KB LDS, 1 blk/CU.
//  - STAGE(c+1) + mask-prefetch issued at GATE(c) start: only barrier
//    between issue and use is the chunk-top __syncthreads -> ~full-chunk
//    (~1-2Kcy) latency cover, no early vmcnt drain (mid-chunk barriers
//    precede the issue). All barriers remain plain __syncthreads (no race).
//  - scores read MFMA frags from LDS; mask from regs (prefetched 1 chunk
//    ahead); gate reads lv/rv/atts from LDS (v11 shapes kept).
// ---------------------------------------------------------------------------
__global__ __launch_bounds__(512, 2) void fused_attn(const ushort* __restrict__ P,
                                                     const unsigned char* __restrict__ mask,
                                                     ushort* __restrict__ xbuf) {
    // LKb/LVb: [buf][x16][a16][dk32] bf16; RKb/RVb: [buf][a16][y16][dk32] bf16.
    // atts: f32 [(a*16+y)][20] with x = 0..15 in the stride-20 row.
    __shared__ __align__(16) ushort LKb[2][16 * 512];
    __shared__ __align__(16) ushort RKb[2][16 * 512];
    __shared__ __align__(16) ushort LVb[2][16 * 512];
    __shared__ __align__(16) ushort RVb[2][16 * 512];
    __shared__ __align__(16) float atts[16 * 16 * 20];
    __shared__ float mstate[16 * 20];
    __shared__ float alphas[16 * 20];

    const int bh = blockIdx.z;
    const int b = bh >> 3, h = bh & 7;
    const int x0 = blockIdx.x * 16, y0 = blockIdx.y * 16;
    const int tid = threadIdx.x;
    const int lane = tid & 63, wave = tid >> 6;

    const size_t HB = (size_t)bh * 4096 * 32;   // head slice offset (elements)
    const ushort* PLK = P + HB;
    const ushort* PRK = P + (size_t)1 * PROJ_ELEMS + HB;
    const ushort* PLV = P + (size_t)2 * PROJ_ELEMS + HB;
    const ushort* PRV = P + (size_t)3 * PROJ_ELEMS + HB;

    // gate coords: x = wave*2 + i, y = y0 + gy, d = du*8 + 2q + {0,1}
    const int gy = lane >> 2;   // 0..15
    const int du = lane & 3;    // 0..3 (16B quarter of the 64B dk row)
    // scores coords
    const int fr = lane & 15, fk = (lane >> 4) * 8;
    const int yq = lane & 15, xq = (lane >> 4) * 4;
    // softmax coords (threads 0..255): thread owns (x=sx, y=sy)
    const int sx = tid >> 4, sy = tid & 15;
    if (tid < 256) mstate[sx * 20 + sy] = -3.0e38f;

    // staging lane mapping (per glds16: 16 rows x 32 dk, 16B/lane)
    const int sa = lane >> 2, soct = lane & 3;
    const int r2 = wave * 2;   // this wave's pair of x-slabs (LK/LV) / a-slabs (RK/RV)

    f32x2 acc[2][4] = {};
    float lacc[2] = {0.0f, 0.0f};
    const float scale = 0.17677669529663687f; // 1/sqrt(32)

    unsigned char mreg[2][4];

    // stage chunk (ac_) into buffer buf_: 8 glds16 per wave
#define STAGE(ac_, buf_)                                                                      \
    do {                                                                                      \
        glds16(PLK + ((size_t)(x0 + r2) * 64 + (ac_) + sa) * 32 + soct * 8,                   \
               &LKb[buf_][r2 * 512]);                                                         \
        glds16(PLK + ((size_t)(x0 + r2 + 1) * 64 + (ac_) + sa) * 32 + soct * 8,               \
               &LKb[buf_][(r2 + 1) * 512]);                                                   \
        glds16(PLV + ((size_t)(x0 + r2) * 64 + (ac_) + sa) * 32 + soct * 8,                   \
               &LVb[buf_][r2 * 512]);                                                         \
        glds16(PLV + ((size_t)(x0 + r2 + 1) * 64 + (ac_) + sa) * 32 + soct * 8,               \
               &LVb[buf_][(r2 + 1) * 512]);                                                   \
        glds16(PRK + ((size_t)((ac_) + r2) * 64 + y0 + sa) * 32 + soct * 8,                   \
               &RKb[buf_][r2 * 512]);                                                         \
        glds16(PRK + ((size_t)((ac_) + r2 + 1) * 64 + y0 + sa) * 32 + soct * 8,               \
               &RKb[buf_][(r2 + 1) * 512]);                                                   \
        glds16(PRV + ((size_t)((ac_) + r2) * 64 + y0 + sa) * 32 + soct * 8,                   \
               &RVb[buf_][r2 * 512]);                                                         \
        glds16(PRV + ((size_t)((ac_) + r2 + 1) * 64 + y0 + sa) * 32 + soct * 8,               \
               &RVb[buf_][(r2 + 1) * 512]);                                                   \
    } while (0)

#define MLOAD(ac_)                                                                            \
    do {                                                                                      \
        _Pragma("unroll") for (int aw = 0; aw < 2; ++aw)                                      \
        _Pragma("unroll") for (int rr = 0; rr < 4; ++rr)                                      \
            mreg[aw][rr] = mask[((size_t)(b * N + x0 + xq + rr) * N + (ac_) + wave * 2 + aw)  \
                                    * N + y0 + yq];                                           \
    } while (0)

    // prologue: chunk 0 in flight; drained by first chunk-top barrier
    STAGE(0, 0);
    MLOAD(0);

    for (int c = 0; c < 4; ++c) {
        const int cur = c & 1;
        __syncthreads();  // drains STAGE(c)+MLOAD(c); all waves past gate(c-1)

        // ---- scores: frags from LDS, mask from regs (2 a per wave) ----
#pragma unroll
        for (int aw = 0; aw < 2; ++aw) {
            const int al = wave * 2 + aw;  // a-index within chunk
            bf16x8 af = *(const bf16x8*)&LKb[cur][fr * 512 + al * 32 + fk];
            bf16x8 bf = *(const bf16x8*)&RKb[cur][al * 512 + fr * 32 + fk];
            f32x4 s = {};
            s = __builtin_amdgcn_mfma_f32_16x16x32_bf16(af, bf, s, 0, 0, 0);
            float4 ov;
            float* op = (float*)&ov;
#pragma unroll
            for (int rr = 0; rr < 4; ++rr) {
                float sv = s[rr] * scale;
                if (mreg[aw][rr]) sv = -1000.0f;
                op[rr] = sv;
            }
            *(float4*)&atts[(al * 16 + yq) * 20 + xq] = ov;  // [a][y][x], 1 b128
        }
        __syncthreads();  // atts visible (nothing in vmcnt flight)

        // ---- online max over 16-a chunk: max + alpha only ----
        if (tid < 256) {
            float mc = -3.0e38f;
#pragma unroll
            for (int a = 0; a < 16; ++a) mc = fmaxf(mc, atts[(a * 16 + sy) * 20 + sx]);
            const float mold = mstate[sx * 20 + sy];
            const float mnew = fmaxf(mold, mc);
            mstate[sx * 20 + sy] = mnew;
            alphas[sx * 20 + sy] = __expf(mold - mnew);
        }
        __syncthreads();  // alphas/mstate visible

        // ---- issue next chunk's staging + mask (hides under the gate) ----
        if (c < 3) {
            STAGE((c + 1) * 16, cur ^ 1);
            MLOAD((c + 1) * 16);
        }

        // ---- rescale (acc and running l in regs) ----
        float mn[2];
#pragma unroll
        for (int i = 0; i < 2; ++i) {
            const int x = wave * 2 + i;
            const float av = alphas[x * 20 + gy];
            mn[i] = mstate[x * 20 + gy];
            lacc[i] *= av;
#pragma unroll
            for (int q = 0; q < 4; ++q) acc[i][q] *= av;
        }

        // ---- gate: lv (bcast b128) + rv (full-row b128) + atts (b64) ----
        {
            const unsigned* LV32 = (const unsigned*)&LVb[cur][0];
            const unsigned* RV32 = (const unsigned*)&RVb[cur][0];
#pragma unroll
            for (int a = 0; a < 16; ++a) {
                const uint4 lv0 = *(const uint4*)&LV32[(wave * 2) * 256 + a * 16 + du * 4];
                const uint4 lv1 = *(const uint4*)&LV32[(wave * 2 + 1) * 256 + a * 16 + du * 4];
                const uint4 rvw = *(const uint4*)&RV32[a * 256 + gy * 16 + du * 4];
                const float2 w2 = *(const float2*)&atts[(a * 16 + gy) * 20 + wave * 2];
                const float w0 = __expf(w2.x - mn[0]);
                const float w1 = __expf(w2.y - mn[1]);
                lacc[0] += w0;
                lacc[1] += w1;
                const f32x2 rv0 = up2(rvw.x), rv1 = up2(rvw.y);
                const f32x2 rv2 = up2(rvw.z), rv3 = up2(rvw.w);
                acc[0][0] += (up2(lv0.x) * w0) * rv0;
                acc[0][1] += (up2(lv0.y) * w0) * rv1;
                acc[0][2] += (up2(lv0.z) * w0) * rv2;
                acc[0][3] += (up2(lv0.w) * w0) * rv3;
                acc[1][0] += (up2(lv1.x) * w1) * rv0;
                acc[1][1] += (up2(lv1.y) * w1) * rv1;
                acc[1][2] += (up2(lv1.z) * w1) * rv2;
                acc[1][3] += (up2(lv1.w) * w1) * rv3;
            }
        }
    }

    // ---- epilogue: divide by l (regs), one 16B store per x ----
#pragma unroll
    for (int i = 0; i < 2; ++i) {
        const int x = wave * 2 + i;
        const float il = 1.0f / lacc[i];
        ushort o[8] __attribute__((aligned(16)));
#pragma unroll
        for (int q = 0; q < 4; ++q) {
            o[2 * q]     = f2b(acc[i][q].x * il);
            o[2 * q + 1] = f2b(acc[i][q].y * il);
        }
        *(uint4*)&xbuf[(((size_t)b * N + x0 + x) * N + y0 + gy) * D + h * DK + du * 8] =
            *(const uint4*)o;
    }
#undef STAGE
#undef MLOAD
}

// ---------------------------------------------------------------------------
extern "C" void kernel_launch(void* const* d_in, const int* in_sizes, int n_in,
                              void* d_out, int out_size, void* d_ws, size_t ws_size,
                              hipStream_t stream) {
    const float* state = (const float*)d_in[0];
    const unsigned char* mask = (const unsigned char*)d_in[1];
    const float* W_lk = (const float*)d_in[2];
    const float* b_lk = (const float*)d_in[3];
    const float* W_rk = (const float*)d_in[4];
    const float* b_rk = (const float*)d_in[5];
    const float* W_lv = (const float*)d_in[6];
    const float* b_lv = (const float*)d_in[7];
    const float* W_rv = (const float*)d_in[8];
    const float* b_rv = (const float*)d_in[9];
    const float* W_o = (const float*)d_in[10];
    const float* b_o = (const float*)d_in[11];
    float* out = (float*)d_out;

    char* ws = (char*)d_ws;
    ushort* P_bf = (ushort*)ws;                          // 4 proj planes, 16.8 MB
    ws += (size_t)4 * PROJ_ELEMS * 2;
    float* bias_cat = (float*)ws;                        // 1280 f32
    ws += 1280 * 4;
    ushort* state_bf = (ushort*)ws;                      // 4 MB
    ws += (size_t)M * D * 2;
    ushort* Wcat = (ushort*)ws;                          // 0.65 MB
    ws += (size_t)1280 * 256 * 2;
    ushort* xbuf_bf = (ushort*)ws;                       // 4 MB

    cast_all<<<2368, 256, 0, stream>>>(state, W_lk, W_rk, W_lv, W_rv, W_o,
                                       b_lk, b_rk, b_lv, b_rv, b_o,
                                       state_bf, Wcat, bias_cat);
    gemm_mfma<1, 1, 128><<<dim3(M / 128, 8), 256, 0, stream>>>(state_bf, Wcat, bias_cat, P_bf, 1024);
    fused_attn<<<dim3(4, 4, B * H), 512, 0, stream>>>(P_bf, mask, xbuf_bf);
    gemm_mfma<0, 0, 64><<<dim3(M / 64, 2), 256, 0, stream>>>(xbuf_bf, Wcat + 1024 * 256, bias_cat + 1024, out, 256);
}

// Round 9
// 122.295 us; speedup vs baseline: 1.0129x; 1.0129x over previous
//
#include <hip/hip_runtime.h>

#define B 2
#define N 64
#define D 256
#define H 8
#define DK 32
#define M (B * N * N) // 8192

typedef __attribute__((ext_vector_type(8))) short bf16x8;
typedef __attribute__((ext_vector_type(4))) float f32x4;
typedef __attribute__((ext_vector_type(2))) float f32x2;

// P is head-major: 4 proj planes of [b][h][r1*64+r2][32] bf16
#define PROJ_ELEMS (2097152)  // B*H*4096*32

__device__ __forceinline__ ushort f2b(float f) {
    union { float f; unsigned u; } v; v.f = f;
    unsigned r = v.u + 0x7fffu + ((v.u >> 16) & 1u); // RNE
    return (ushort)(r >> 16);
}
__device__ __forceinline__ float b2f(ushort u) {
    union { unsigned u; float f; } v; v.u = ((unsigned)u) << 16; return v.f;
}
// unpack 2 packed bf16 (u32) -> float2
__device__ __forceinline__ f32x2 up2(unsigned u) {
    union { unsigned u; float f; } lo, hi;
    lo.u = u << 16; hi.u = u & 0xffff0000u;
    f32x2 r; r.x = lo.f; r.y = hi.f; return r;
}

// async 16B/lane global->LDS (dst = wave-uniform base + lane*16)
__device__ __forceinline__ void glds16(const ushort* g, ushort* l) {
    __builtin_amdgcn_global_load_lds(
        (const __attribute__((address_space(1))) unsigned int*)g,
        (__attribute__((address_space(3))) unsigned int*)l, 16, 0, 0);
}

// ---------------------------------------------------------------------------
// Cast: state f32 -> bf16; 5 weights -> Wcat[1280][256] bf16; biases -> f32.
// ---------------------------------------------------------------------------
__global__ __launch_bounds__(256) void cast_all(const float* __restrict__ state,
                                                const float* __restrict__ W_lk, const float* __restrict__ W_rk,
                                                const float* __restrict__ W_lv, const float* __restrict__ W_rv,
                                                const float* __restrict__ W_o,
                                                const float* __restrict__ b_lk, const float* __restrict__ b_rk,
                                                const float* __restrict__ b_lv, const float* __restrict__ b_rv,
                                                const float* __restrict__ b_o,
                                                ushort* __restrict__ state_bf,
                                                ushort* __restrict__ Wcat,
                                                float* __restrict__ bias_cat) {
    const int gid = blockIdx.x * 256 + threadIdx.x;
    const float* Ws[5] = {W_lk, W_rk, W_lv, W_rv, W_o};
    const float* bs[5] = {b_lk, b_rk, b_lv, b_rv, b_o};

    if (gid < 1280) bias_cat[gid] = bs[gid >> 8][gid & 255];

    if (gid < 524288) {
        float4 v = *(const float4*)&state[(size_t)gid * 4];
        ushort4 o = {f2b(v.x), f2b(v.y), f2b(v.z), f2b(v.w)};
        *(ushort4*)&state_bf[(size_t)gid * 4] = o;
    } else {
        int u = gid - 524288;            // 0..81919
        int row = u >> 6;                // 0..1279
        int k4 = (u & 63) * 4;
        const float* W = Ws[row >> 8];
        float4 v = *(const float4*)&W[(size_t)(row & 255) * 256 + k4];
        ushort4 o = {f2b(v.x), f2b(v.y), f2b(v.z), f2b(v.w)};
        *(ushort4*)&Wcat[(size_t)row * 256 + k4] = o;
    }
}

// ---------------------------------------------------------------------------
// bf16 MFMA GEMM, v10 (unchanged): BM x 128 tile, 4 waves, pipelined staging.
// ---------------------------------------------------------------------------
template <int BF16OUT, int RELAYOUT, int BM>
__global__ __launch_bounds__(256) void gemm_mfma(const ushort* __restrict__ A,
                                                 const ushort* __restrict__ Bw,
                                                 const float* __restrict__ bias,
                                                 void* __restrict__ Cv, int ldc) {
    constexpr int IR = BM / 32;  // 128 -> 4, 64 -> 2 (acc row-frags per wave)
    __shared__ __align__(16) ushort As[2][2][BM * 32];
    __shared__ __align__(16) ushort Bs[2][2][128 * 32];
    const int tid = threadIdx.x;
    const int lane = tid & 63;
    const int wave = tid >> 6;
    const int wm = (wave & 1) * (BM / 2);
    const int wn = (wave >> 1) * 64;
    const int row0 = blockIdx.x * BM;
    const int col0 = blockIdx.y * 128;

    const int lr = lane >> 2;        // 0..15
    const int lkq = (lane & 3) * 8;  // {0,8,16,24}

    const int arow = (BM == 128) ? (wave * 32) : (wave * 16);
    const ushort* gA0 = A + (size_t)(row0 + arow + lr) * 256 + lkq;
    const ushort* gA1 = gA0 + 16 * 256;  // BM==128 only
    const ushort* gB0 = Bw + (size_t)(col0 + wave * 32 + lr) * 256 + lkq;
    const ushort* gB1 = gB0 + 16 * 256;

    const int fr = lane & 15;
    const int fk = (lane >> 4) * 8;

    f32x4 acc[IR][4] = {};

    auto stage2 = [&](int grp) {
        const int buf = grp & 1;
#pragma unroll
        for (int p = 0; p < 2; ++p) {
            const int ko = (grp * 2 + p) * 32;
            glds16(gA0 + ko, &As[buf][p][arow * 32]);
            if (BM == 128) glds16(gA1 + ko, &As[buf][p][(arow + 16) * 32]);
            glds16(gB0 + ko, &Bs[buf][p][(wave * 32) * 32]);
            glds16(gB1 + ko, &Bs[buf][p][(wave * 32 + 16) * 32]);
        }
    };

    stage2(0);
    __syncthreads();  // drain prologue

    for (int it = 0; it < 4; ++it) {
        if (it < 3) stage2(it + 1);  // issue next pair; drains at loop barrier
        const int buf = it & 1;
#pragma unroll
        for (int p = 0; p < 2; ++p) {
            bf16x8 af[IR], bf[4];
#pragma unroll
            for (int i = 0; i < IR; ++i)
                af[i] = *(const bf16x8*)&As[buf][p][(wm + i * 16 + fr) * 32 + fk];
#pragma unroll
            for (int j = 0; j < 4; ++j)
                bf[j] = *(const bf16x8*)&Bs[buf][p][(wn + j * 16 + fr) * 32 + fk];
#pragma unroll
            for (int i = 0; i < IR; ++i)
#pragma unroll
                for (int j = 0; j < 4; ++j)
                    acc[i][j] = __builtin_amdgcn_mfma_f32_16x16x32_bf16(af[i], bf[j], acc[i][j], 0, 0, 0);
        }
        __syncthreads();  // drain stage(it+1); protect buf reuse
    }

#pragma unroll
    for (int j = 0; j < 4; ++j) {
        const int col = col0 + wn + j * 16 + (lane & 15);
        const float bv = bias[col];
#pragma unroll
        for (int i = 0; i < IR; ++i) {
            const int rbase = row0 + wm + i * 16 + (lane >> 4) * 4;
#pragma unroll
            for (int r = 0; r < 4; ++r) {
                float o = acc[i][j][r] + bv;
                if (RELAYOUT) {
                    const int row = rbase + r;
                    const int bb = row >> 12, rr = row & 4095;
                    const int proj = col >> 8, hh = (col >> 5) & 7, dk = col & 31;
                    ((ushort*)Cv)[(size_t)proj * PROJ_ELEMS +
                                  ((size_t)(bb * 8 + hh) * 4096 + rr) * 32 + dk] = f2b(o);
                } else if (BF16OUT) {
                    ((ushort*)Cv)[(size_t)(rbase + r) * ldc + col] = f2b(o);
                } else {
                    ((float*)Cv)[(size_t)(rbase + r) * ldc + col] = o;
                }
            }
        }
    }
}

// ---------------------------------------------------------------------------
// FUSED scores + online-softmax + gated combine, v13 (resubmit — r8 bench
// failed on GPU acquisition, kernel never ran).
// r6/r7 post-mortem: total time invariant across 3 attn structures ->
// attn is latency-bound at 2 waves/SIMD (r6: VALU 24%, occ 19.6%). v13
// attacks PARALLELISM + LDS redundancy:
//  - 1024 threads (16 waves = 4 waves/SIMD, 2x TLP); per-wave work halved.
//  - gate wave = (x-group xg, d-quad du); lanes = (xi, y). Per a-step:
//    rv read = 16 unique granules x 4-bcast (2-way banks = free); lv =
//    4-granule bcast (free); atts b32 2-way (free).
//  - LK/LV/RV tiles use 520-ushort row pitch ([x|y][a][dk]): every gate
//    and score read audits to <=2-way banks. RK stays [a][y][dk].
//  - scores: 1 MFMA per wave (wave = a). 3 barriers/chunk, a-chunk 16,
//    double-buffered glds16 with issue-in-gate (v12's proven placement).
// LDS: 152 KB, 1 block/CU, 16 waves = 4 waves/SIMD.
// ---------------------------------------------------------------------------
__global__ __launch_bounds__(1024, 1) void fused_attn(const ushort* __restrict__ P,
                                                      const unsigned char* __restrict__ mask,
                                                      ushort* __restrict__ xbuf) {
    // LKb/LVb: [x16][a16][dk32] rows padded to 520; RVb: [y16][a16][dk32] pad 520;
    // RKb: [a16][y16][dk32] unpadded. atts: f32 [(a*16+y)][20] (x in row).
    __shared__ __align__(16) ushort LKb[2][16 * 520];
    __shared__ __align__(16) ushort LVb[2][16 * 520];
    __shared__ __align__(16) ushort RVb[2][16 * 520];
    __shared__ __align__(16) ushort RKb[2][16 * 512];
    __shared__ __align__(16) float atts[16 * 16 * 20];
    __shared__ float mstate[16 * 20];
    __shared__ float alphas[16 * 20];

    const int bh = blockIdx.z;
    const int b = bh >> 3, h = bh & 7;
    const int x0 = blockIdx.x * 16, y0 = blockIdx.y * 16;
    const int tid = threadIdx.x;
    const int lane = tid & 63, wave = tid >> 6;   // 16 waves

    const size_t HB = (size_t)bh * 4096 * 32;   // head slice offset (elements)
    const ushort* PLK = P + HB;
    const ushort* PRK = P + (size_t)1 * PROJ_ELEMS + HB;
    const ushort* PLV = P + (size_t)2 * PROJ_ELEMS + HB;
    const ushort* PRV = P + (size_t)3 * PROJ_ELEMS + HB;

    // scores coords (wave = a within chunk)
    const int fr = lane & 15, fk = (lane >> 4) * 8;
    const int yq = lane & 15, xq = (lane >> 4) * 4;
    // gate coords: wave = (xg, du); lane = (xi, gy). x = xg*4+xi.
    const int xg = wave >> 2, du = wave & 3;
    const int xi = lane >> 4, gy = lane & 15;
    const int gx = xg * 4 + xi;
    // softmax coords (threads 0..255): thread owns (x=sx, y=sy)
    const int sx = tid >> 4, sy = tid & 15;
    if (tid < 256) mstate[sx * 20 + sy] = -3.0e38f;

    // staging: wave -> plane (wave>>2), 4 rows (wave&3)*4..+3.
    // per glds16: lane (sa = a-idx or y-idx, soct) covers 16 rows x 32 dk.
    const int splane = wave >> 2, srow0 = (wave & 3) * 4;
    const int sa = lane >> 2, soct = lane & 3;

    f32x2 acc[4] = {};
    float lacc = 0.0f;
    const float scale = 0.17677669529663687f; // 1/sqrt(32)

    unsigned char mreg[4];

#define STAGE(ac_, buf_)                                                                      \
    do {                                                                                      \
        _Pragma("unroll") for (int rr4 = 0; rr4 < 4; ++rr4) {                                 \
            const int row = srow0 + rr4;                                                      \
            if (splane == 0)                                                                  \
                glds16(PLK + ((size_t)(x0 + row) * 64 + (ac_) + sa) * 32 + soct * 8,          \
                       &LKb[buf_][row * 520]);                                                \
            else if (splane == 1)                                                             \
                glds16(PLV + ((size_t)(x0 + row) * 64 + (ac_) + sa) * 32 + soct * 8,          \
                       &LVb[buf_][row * 520]);                                                \
            else if (splane == 2)                                                             \
                glds16(PRV + ((size_t)((ac_) + sa) * 64 + y0 + row) * 32 + soct * 8,          \
                       &RVb[buf_][row * 520]);                                                \
            else                                                                              \
                glds16(PRK + ((size_t)((ac_) + row) * 64 + y0 + sa) * 32 + soct * 8,          \
                       &RKb[buf_][row * 512]);                                                \
        }                                                                                     \
    } while (0)

#define MLOAD(ac_)                                                                            \
    do {                                                                                      \
        _Pragma("unroll") for (int rr = 0; rr < 4; ++rr)                                      \
            mreg[rr] = mask[((size_t)(b * N + x0 + xq + rr) * N + (ac_) + wave) * N +         \
                            y0 + yq];                                                         \
    } while (0)

    // prologue: chunk 0 in flight; drained at first chunk-top barrier
    STAGE(0, 0);
    MLOAD(0);

    for (int c = 0; c < 4; ++c) {
        const int cur = c & 1;
        __syncthreads();  // drains STAGE(c)+MLOAD(c); all waves past gate(c-1)

        // ---- scores: 1 MFMA per wave (a = wave), frags from LDS ----
        {
            bf16x8 af = *(const bf16x8*)&LKb[cur][fr * 520 + wave * 32 + fk];
            bf16x8 bf = *(const bf16x8*)&RKb[cur][wave * 512 + fr * 32 + fk];
            f32x4 s = {};
            s = __builtin_amdgcn_mfma_f32_16x16x32_bf16(af, bf, s, 0, 0, 0);
            float4 ov;
            float* op = (float*)&ov;
#pragma unroll
            for (int rr = 0; rr < 4; ++rr) {
                float sv = s[rr] * scale;
                if (mreg[rr]) sv = -1000.0f;
                op[rr] = sv;
            }
            *(float4*)&atts[(wave * 16 + yq) * 20 + xq] = ov;  // [a][y][x], 1 b128
        }
        __syncthreads();  // atts visible

        // ---- online max over 16-a chunk: max + alpha only (waves 0-3) ----
        if (tid < 256) {
            float mc = -3.0e38f;
#pragma unroll
            for (int a = 0; a < 16; ++a) mc = fmaxf(mc, atts[(a * 16 + sy) * 20 + sx]);
            const float mold = mstate[sx * 20 + sy];
            const float mnew = fmaxf(mold, mc);
            mstate[sx * 20 + sy] = mnew;
            alphas[sx * 20 + sy] = __expf(mold - mnew);
        }
        __syncthreads();  // alphas/mstate visible

        // ---- issue next chunk's staging + mask (hides under the gate) ----
        if (c < 3) {
            STAGE((c + 1) * 16, cur ^ 1);
            MLOAD((c + 1) * 16);
        }

        // ---- rescale (acc and running l in regs) ----
        {
            const float av = alphas[gx * 20 + gy];
            lacc *= av;
#pragma unroll
            for (int q = 0; q < 4; ++q) acc[q] *= av;
        }
        const float mnv = mstate[gx * 20 + gy];

        // ---- gate: per a: rv 16-granule (2-way), lv 4-granule bcast,
        //      atts b32 (2-way); 1 exp; 8 pk-fma ----
        {
            const unsigned* LV32 = (const unsigned*)&LVb[cur][0];
            const unsigned* RV32 = (const unsigned*)&RVb[cur][0];
#pragma unroll
            for (int a = 0; a < 16; ++a) {
                const uint4 lvw = *(const uint4*)&LV32[gx * 260 + a * 16 + du * 4];
                const uint4 rvw = *(const uint4*)&RV32[gy * 260 + a * 16 + du * 4];
                const float w = __expf(atts[(a * 16 + gy) * 20 + gx] - mnv);
                lacc += w;
                acc[0] += (up2(lvw.x) * w) * up2(rvw.x);
                acc[1] += (up2(lvw.y) * w) * up2(rvw.y);
                acc[2] += (up2(lvw.z) * w) * up2(rvw.z);
                acc[3] += (up2(lvw.w) * w) * up2(rvw.w);
            }
        }
    }

    // ---- epilogue: divide by l (regs), one 16B store per thread ----
    {
        const float il = 1.0f / lacc;
        ushort o[8] __attribute__((aligned(16)));
#pragma unroll
        for (int q = 0; q < 4; ++q) {
            o[2 * q]     = f2b(acc[q].x * il);
            o[2 * q + 1] = f2b(acc[q].y * il);
        }
        *(uint4*)&xbuf[(((size_t)b * N + x0 + gx) * N + y0 + gy) * D + h * DK + du * 8] =
            *(const uint4*)o;
    }
#undef STAGE
#undef MLOAD
}

// ---------------------------------------------------------------------------
extern "C" void kernel_launch(void* const* d_in, const int* in_sizes, int n_in,
                              void* d_out, int out_size, void* d_ws, size_t ws_size,
                              hipStream_t stream) {
    const float* state = (const float*)d_in[0];
    const unsigned char* mask = (const unsigned char*)d_in[1];
    const float* W_lk = (const float*)d_in[2];
    const float* b_lk = (const float*)d_in[3];
    const float* W_rk = (const float*)d_in[4];
    const float* b_rk = (const float*)d_in[5];
    const float* W_lv = (const float*)d_in[6];
    const float* b_lv = (const float*)d_in[7];
    const float* W_rv = (const float*)d_in[8];
    const float* b_rv = (const float*)d_in[9];
    const float* W_o = (const float*)d_in[10];
    const float* b_o = (const float*)d_in[11];
    float* out = (float*)d_out;

    char* ws = (char*)d_ws;
    ushort* P_bf = (ushort*)ws;                          // 4 proj planes, 16.8 MB
    ws += (size_t)4 * PROJ_ELEMS * 2;
    float* bias_cat = (float*)ws;                        // 1280 f32
    ws += 1280 * 4;
    ushort* state_bf = (ushort*)ws;                      // 4 MB
    ws += (size_t)M * D * 2;
    ushort* Wcat = (ushort*)ws;                          // 0.65 MB
    ws += (size_t)1280 * 256 * 2;
    ushort* xbuf_bf = (ushort*)ws;                       // 4 MB

    cast_all<<<2368, 256, 0, stream>>>(state, W_lk, W_rk, W_lv, W_rv, W_o,
                                       b_lk, b_rk, b_lv, b_rv, b_o,
                                       state_bf, Wcat, bias_cat);
    gemm_mfma<1, 1, 128><<<dim3(M / 128, 8), 256, 0, stream>>>(state_bf, Wcat, bias_cat, P_bf, 1024);
    fused_attn<<<dim3(4, 4, B * H), 1024, 0, stream>>>(P_bf, mask, xbuf_bf);
    gemm_mfma<0, 0, 64><<<dim3(M / 64, 2), 256, 0, stream>>>(xbuf_bf, Wcat + 1024 * 256, bias_cat + 1024, out, 256);
}